// Round 1
// baseline (73995.074 us; speedup 1.0000x reference)
//
#include <hip/hip_runtime.h>
#include <math.h>

#define B   16
#define H   512
#define G4  2048      // 4*H gate rows per layer
#define V   32000
#define T   300
#define NBLK 256
#define VPB  125      // vocab rows per block (V / NBLK)
#define LSTR 516      // LDS row stride (pad 512 -> 516: 2-way bank aliasing only, free)

// ws layout (float offsets):
//  h0[2] : 0      (2 * 8192)
//  h1[2] : 16384  (2 * 8192)
//  c0    : 32768  (8192)
//  c1    : 40960  (8192)
//  pval  : 49152  (256*16 floats)
//  pidx  : 53248  (256*16 ints)
//  flags : 57344  (256 barrier flags, stride 16 u32 = one 64B line each)
#define WS_H0   0
#define WS_H1   16384
#define WS_C0   32768
#define WS_C1   40960
#define WS_PVAL 49152
#define WS_PIDX 53248
#define WS_BAR  57344
#define WS_FLOATS (57344 + 4096)

__device__ __forceinline__ float sigf(float v) { return 1.0f / (1.0f + expf(-v)); }

// Grid barrier: per-block monotonic epoch flag (64B-strided), 256-way parallel poll.
// Release: __threadfence (wb L2, device scope) + release store of epoch.
// Acquire: poll relaxed agent-scope loads, then __threadfence (invalidate L1/L2-remote).
__device__ __forceinline__ void gridbar(unsigned* flags, unsigned target) {
    __syncthreads();
    __threadfence();
    if (threadIdx.x == 0) {
        __hip_atomic_store(&flags[blockIdx.x * 16], target,
                           __ATOMIC_RELEASE, __HIP_MEMORY_SCOPE_AGENT);
    }
    if (threadIdx.x < NBLK) {
        while (__hip_atomic_load(&flags[threadIdx.x * 16],
                                 __ATOMIC_RELAXED, __HIP_MEMORY_SCOPE_AGENT) < target) {
            __builtin_amdgcn_s_sleep(1);
        }
    }
    __syncthreads();
    __threadfence();
}

// One LSTM layer, 512 threads. Block bid owns hidden dims {2*bid, 2*bid+1}.
// Gate dot: thread = (b:16, gate:4, dim-half:2, k-split:4), k-chunk 128.
__device__ __forceinline__ void lstm_layer(
    int tid, int bid,
    const float* __restrict__ Wa, const float* __restrict__ Wb_,
    const float* __restrict__ bi, const float* __restrict__ bh,
    const float* __restrict__ hsrc, float* __restrict__ cptr, float* __restrict__ hout,
    const float* __restrict__ eg,            // dense input base (stride H), used if !use_idx
    const float* __restrict__ Wt, const int* idx_lds, int use_idx,
    float* e_lds, float* h_lds, float* partial, float* gate_lds)
{
    // ---- stage e (input) and h (recurrent) into LDS, coalesced float4 ----
    for (int i = 0; i < 4; ++i) {
        int j = tid + 512 * i;                // 2048 float4 total
        int b = j >> 7, k4 = (j & 127) << 2;
        const float4* es = use_idx
            ? (const float4*)(Wt + (long)idx_lds[b] * H + k4)
            : (const float4*)(eg + b * H + k4);
        *(float4*)&e_lds[b * LSTR + k4] = *es;
        *(float4*)&h_lds[b * LSTR + k4] = *(const float4*)(hsrc + b * H + k4);
    }
    __syncthreads();

    {
        int b = tid & 15, g = (tid >> 4) & 3, dh = (tid >> 6) & 1, ks = tid >> 7;
        int row = (g << 9) + bid * 2 + dh;
        const float* wa  = Wa  + (long)row * H;
        const float* wb2 = Wb_ + (long)row * H;
        const float* ep_ = &e_lds[b * LSTR];
        const float* hp  = &h_lds[b * LSTR];
        float acc = 0.0f;
        int k0 = ks * 128;
        #pragma unroll 8
        for (int k = k0; k < k0 + 128; k += 4) {
            float4 w1 = *(const float4*)(wa + k);
            float4 e1 = *(const float4*)(ep_ + k);
            acc += w1.x * e1.x + w1.y * e1.y + w1.z * e1.z + w1.w * e1.w;
            float4 w2 = *(const float4*)(wb2 + k);
            float4 h1 = *(const float4*)(hp + k);
            acc += w2.x * h1.x + w2.y * h1.y + w2.z * h1.z + w2.w * h1.w;
        }
        partial[tid] = acc;
    }
    __syncthreads();
    if (tid < 128) {
        int b = tid & 15, g = (tid >> 4) & 3, dh = tid >> 6;
        int row = (g << 9) + bid * 2 + dh;
        float s = partial[tid] + partial[tid + 128] + partial[tid + 256] + partial[tid + 384]
                + bi[row] + bh[row];
        gate_lds[b * 8 + dh * 4 + g] = s;
    }
    __syncthreads();
    if (tid < 32) {
        int b = tid & 15, dh = tid >> 4;
        int d = bid * 2 + dh;
        float gi = gate_lds[b * 8 + dh * 4 + 0];
        float gf = gate_lds[b * 8 + dh * 4 + 1];
        float gg = gate_lds[b * 8 + dh * 4 + 2];
        float go = gate_lds[b * 8 + dh * 4 + 3];
        float co = cptr[b * H + d];
        float cn = sigf(gf) * co + sigf(gi) * tanhf(gg);
        float hn = sigf(go) * tanhf(cn);
        cptr[b * H + d] = cn;
        hout[b * H + d] = hn;
    }
}

// Persistent fused kernel: all T=300 steps, 3 grid barriers per step.
__global__ __launch_bounds__(512) void fused_kernel(
    const float* __restrict__ x,  const float* __restrict__ Wt,
    const float* __restrict__ bpred,
    const float* __restrict__ Wih, const float* __restrict__ Whh,
    const float* __restrict__ bih, const float* __restrict__ bhh,
    float* __restrict__ ws, float* __restrict__ out)
{
    __shared__ __align__(16) float e_lds[B * LSTR];
    __shared__ __align__(16) float h_lds[B * LSTR];
    __shared__ float partial[512];
    __shared__ float gate_lds[B * 8];
    __shared__ float rv[256];
    __shared__ int   ri[256];
    __shared__ int   idx_lds[B];
    __shared__ float red_v[512];
    __shared__ int   red_i[512];

    const int tid = threadIdx.x, bid = blockIdx.x;
    unsigned* flags = (unsigned*)ws + WS_BAR;
    float* pval = ws + WS_PVAL;
    int*   pidx = (int*)(ws + WS_PIDX);
    unsigned ep = 0;

    for (int t = 0; t < T; ++t) {
        const int rb = t & 1, wb = rb ^ 1;

        // ================= phase A: layer 0 =================
        if (t > 0) {
            // redundant per-block argmax reduce over 256 partials
            if (tid < 256) {
                int b = tid & 15, ch = tid >> 4;
                float bv = -1e30f; int bx = 0x7fffffff;
                for (int j = 0; j < 16; ++j) {
                    int blk = ch * 16 + j;
                    float v = pval[blk * 16 + b];
                    int   i = pidx[blk * 16 + b];
                    if (v > bv || (v == bv && i < bx)) { bv = v; bx = i; }
                }
                rv[tid] = bv; ri[tid] = bx;
            }
            __syncthreads();
            if (tid < 16) {
                float bv = -1e30f; int bx = 0x7fffffff;
                for (int ch = 0; ch < 16; ++ch) {
                    float v = rv[ch * 16 + tid]; int i = ri[ch * 16 + tid];
                    if (v > bv || (v == bv && i < bx)) { bv = v; bx = i; }
                }
                idx_lds[tid] = bx;
            }
            __syncthreads();
        }
        lstm_layer(tid, bid,
                   Wih, Whh, bih, bhh,
                   ws + WS_H0 + rb * 8192, ws + WS_C0, ws + WS_H0 + wb * 8192,
                   x, Wt, idx_lds, (t > 0) ? 1 : 0,
                   e_lds, h_lds, partial, gate_lds);
        gridbar(flags, ++ep);

        // ================= phase B: layer 1 =================
        lstm_layer(tid, bid,
                   Wih + (long)G4 * H, Whh + (long)G4 * H, bih + G4, bhh + G4,
                   ws + WS_H1 + rb * 8192, ws + WS_C1, ws + WS_H1 + wb * 8192,
                   ws + WS_H0 + wb * 8192, Wt, idx_lds, 0,
                   e_lds, h_lds, partial, gate_lds);
        gridbar(flags, ++ep);

        // ================= phase C: logits + partial argmax =================
        {
            const float* h1 = ws + WS_H1 + wb * 8192;
            for (int i = 0; i < 4; ++i) {
                int j = tid + 512 * i;                // 2048 float4
                int b = j >> 7, k4 = (j & 127) << 2;
                *(float4*)&h_lds[b * LSTR + k4] = *(const float4*)(h1 + b * H + k4);
            }
        }
        __syncthreads();
        {
            const int tb = tid & 15, tv = tid >> 4;
            const int vbase = bid * VPB;
            const int v0 = vbase + tv;
            const bool val3 = (tv + 96) < VPB;        // tv < 29
            const float* w0 = Wt + (long)v0 * H;
            const long off3 = val3 ? (long)96 * H : 0;
            const float* hp = &h_lds[tb * LSTR];

            float acc0 = 0.f, acc1 = 0.f, acc2 = 0.f, acc3 = 0.f;
            #pragma unroll 4
            for (int k = 0; k < H; k += 4) {
                float4 hv = *(const float4*)(hp + k);
                float4 a = *(const float4*)(w0 + k);
                acc0 += a.x * hv.x + a.y * hv.y + a.z * hv.z + a.w * hv.w;
                float4 b2 = *(const float4*)(w0 + 32 * H + k);
                acc1 += b2.x * hv.x + b2.y * hv.y + b2.z * hv.z + b2.w * hv.w;
                float4 c2 = *(const float4*)(w0 + 64 * H + k);
                acc2 += c2.x * hv.x + c2.y * hv.y + c2.z * hv.z + c2.w * hv.w;
                float4 d2 = *(const float4*)(w0 + off3 + k);
                acc3 += d2.x * hv.x + d2.y * hv.y + d2.z * hv.z + d2.w * hv.w;
            }

            const long obase = ((long)tb * T + t) * (long)V;
            float l0 = acc0 + bpred[v0];
            float l1 = acc1 + bpred[v0 + 32];
            float l2 = acc2 + bpred[v0 + 64];
            out[obase + v0]      = l0;
            out[obase + v0 + 32] = l1;
            out[obase + v0 + 64] = l2;
            float bv = l0; int bx = v0;
            if (l1 > bv) { bv = l1; bx = v0 + 32; }
            if (l2 > bv) { bv = l2; bx = v0 + 64; }
            if (val3) {
                float l3 = acc3 + bpred[v0 + 96];
                out[obase + v0 + 96] = l3;
                if (l3 > bv) { bv = l3; bx = v0 + 96; }
            }
            red_v[tid] = bv; red_i[tid] = bx;
        }
        __syncthreads();
        if (tid < 16) {
            int b = tid; float bbv = -1e30f; int bbi = 0x7fffffff;
            for (int q = 0; q < 32; ++q) {
                float v = red_v[q * 16 + b]; int i = red_i[q * 16 + b];
                if (v > bbv || (v == bbv && i < bbi)) { bbv = v; bbi = i; }
            }
            pval[bid * 16 + b] = bbv;
            pidx[bid * 16 + b] = bbi;
        }
        gridbar(flags, ++ep);
    }
}

extern "C" void kernel_launch(void* const* d_in, const int* in_sizes, int n_in,
                              void* d_out, int out_size, void* d_ws, size_t ws_size,
                              hipStream_t stream) {
    const float* x   = (const float*)d_in[0];
    const float* Wt  = (const float*)d_in[1];
    const float* bp  = (const float*)d_in[2];
    const float* Wih = (const float*)d_in[3];
    const float* Whh = (const float*)d_in[4];
    const float* bih = (const float*)d_in[5];
    const float* bhh = (const float*)d_in[6];
    float* out = (float*)d_out;
    float* ws  = (float*)d_ws;
    (void)in_sizes; (void)n_in; (void)out_size; (void)ws_size;

    // Zero LSTM state (h,c), argmax partials, and barrier flags every call.
    hipMemsetAsync(d_ws, 0, (size_t)WS_FLOATS * sizeof(float), stream);

    void* args[] = { (void*)&x, (void*)&Wt, (void*)&bp, (void*)&Wih, (void*)&Whh,
                     (void*)&bih, (void*)&bhh, (void*)&ws, (void*)&out };
    hipLaunchCooperativeKernel((void*)fused_kernel, dim3(NBLK), dim3(512),
                               args, 0, stream);
}

// Round 2
// 20406.206 us; speedup vs baseline: 3.6261x; 3.6261x over previous
//
#include <hip/hip_runtime.h>
#include <math.h>

#define B   16
#define H   512
#define G4  2048      // 4*H gate rows per layer
#define V   32000
#define T   300
#define NBLK 256
#define VPB  125      // vocab rows per block (V / NBLK)
#define LSTR 516      // LDS row stride (pad 512 -> 516: 2-way bank aliasing only, free)

// ws layout (float offsets):
//  h0[2] : 0      (2 * 8192)   cross-block (sc1 access)
//  h1[2] : 16384  (2 * 8192)   cross-block (sc1 access)
//  (c is now register-resident per block: threads 0..31 own it)
//  pval  : 49152  (256*16 floats)  cross-block
//  pidx  : 53248  (256*16 ints)    cross-block
//  flags : 57344  (256 barrier flags, stride 16 u32 = one 64B line each)
#define WS_H0   0
#define WS_H1   16384
#define WS_PVAL 49152
#define WS_PIDX 53248
#define WS_BAR  57344
#define WS_FLOATS (57344 + 4096)

__device__ __forceinline__ float sigf(float v) { return 1.0f / (1.0f + expf(-v)); }

// Agent-scope relaxed (monotonic) accesses: compile to global_load/store sc1 —
// bypass the non-coherent per-XCD L2, hit the LLC directly. NO cache-flush
// instructions are emitted (unlike __threadfence, which does buffer_wbl2 /
// buffer_inv and evicts the whole weight working set from L2 every phase).
__device__ __forceinline__ float ld_dev(const float* p) {
    return __hip_atomic_load(p, __ATOMIC_RELAXED, __HIP_MEMORY_SCOPE_AGENT);
}
__device__ __forceinline__ void st_dev(float* p, float v) {
    __hip_atomic_store(p, v, __ATOMIC_RELAXED, __HIP_MEMORY_SCOPE_AGENT);
}
__device__ __forceinline__ int ld_devi(const int* p) {
    return __hip_atomic_load(p, __ATOMIC_RELAXED, __HIP_MEMORY_SCOPE_AGENT);
}
__device__ __forceinline__ void st_devi(int* p, int v) {
    __hip_atomic_store(p, v, __ATOMIC_RELAXED, __HIP_MEMORY_SCOPE_AGENT);
}

// Grid barrier, fence-free. All cross-block payload stores are sc1 (write-through
// to LLC) and issued by wave 0, so a wave-0 vmcnt(0) before the flag store is the
// only ordering needed. Pollers use sc1 loads (always see LLC).
__device__ __forceinline__ void gridbar(unsigned* flags, unsigned target) {
    __syncthreads();
    asm volatile("s_waitcnt vmcnt(0)" ::: "memory");
    if (threadIdx.x == 0) {
        __hip_atomic_store(&flags[blockIdx.x * 16], target,
                           __ATOMIC_RELAXED, __HIP_MEMORY_SCOPE_AGENT);
    }
    if (threadIdx.x < NBLK) {
        while (__hip_atomic_load(&flags[threadIdx.x * 16],
                                 __ATOMIC_RELAXED, __HIP_MEMORY_SCOPE_AGENT) < target) {
            __builtin_amdgcn_s_sleep(1);
        }
    }
    asm volatile("" ::: "memory");
    __syncthreads();
}

// One LSTM layer, 512 threads. Block bid owns hidden dims {2*bid, 2*bid+1}.
// Gate dot: thread = (b:16, gate:4, dim-half:2, k-split:4), k-chunk 128.
// c state lives in a register of threads 0..31 (block-private, persistent kernel).
__device__ __forceinline__ void lstm_layer(
    int tid, int bid,
    const float* __restrict__ Wa, const float* __restrict__ Wb_,
    const float* __restrict__ bi, const float* __restrict__ bh,
    const float* __restrict__ hsrc, float& c_reg, float* __restrict__ hout,
    const float* __restrict__ eg,            // dense input base (stride H, sc1-read)
    const float* __restrict__ Wt, const int* idx_lds, int use_idx,
    float* e_lds, float* h_lds, float* partial, float* gate_lds)
{
    // ---- stage e (input) and h (recurrent) into LDS ----
    // Wt rows (immutable weights): normal cached float4 loads.
    // h-state (cross-block): sc1 scalar loads (independent -> latency-parallel).
    for (int i = 0; i < 4; ++i) {
        int j = tid + 512 * i;                // 2048 float4-slots total
        int b = j >> 7, k4 = (j & 127) << 2;
        if (use_idx) {
            *(float4*)&e_lds[b * LSTR + k4] =
                *(const float4*)(Wt + (long)idx_lds[b] * H + k4);
        } else {
            const float* ep0 = eg + b * H + k4;
            e_lds[b * LSTR + k4 + 0] = ld_dev(ep0 + 0);
            e_lds[b * LSTR + k4 + 1] = ld_dev(ep0 + 1);
            e_lds[b * LSTR + k4 + 2] = ld_dev(ep0 + 2);
            e_lds[b * LSTR + k4 + 3] = ld_dev(ep0 + 3);
        }
        const float* hp0 = hsrc + b * H + k4;
        h_lds[b * LSTR + k4 + 0] = ld_dev(hp0 + 0);
        h_lds[b * LSTR + k4 + 1] = ld_dev(hp0 + 1);
        h_lds[b * LSTR + k4 + 2] = ld_dev(hp0 + 2);
        h_lds[b * LSTR + k4 + 3] = ld_dev(hp0 + 3);
    }
    __syncthreads();

    {
        int b = tid & 15, g = (tid >> 4) & 3, dh = (tid >> 6) & 1, ks = tid >> 7;
        int row = (g << 9) + bid * 2 + dh;
        const float* wa  = Wa  + (long)row * H;
        const float* wb2 = Wb_ + (long)row * H;
        const float* ep_ = &e_lds[b * LSTR];
        const float* hp  = &h_lds[b * LSTR];
        float acc = 0.0f;
        int k0 = ks * 128;
        #pragma unroll 8
        for (int k = k0; k < k0 + 128; k += 4) {
            float4 w1 = *(const float4*)(wa + k);
            float4 e1 = *(const float4*)(ep_ + k);
            acc += w1.x * e1.x + w1.y * e1.y + w1.z * e1.z + w1.w * e1.w;
            float4 w2 = *(const float4*)(wb2 + k);
            float4 h1 = *(const float4*)(hp + k);
            acc += w2.x * h1.x + w2.y * h1.y + w2.z * h1.z + w2.w * h1.w;
        }
        partial[tid] = acc;
    }
    __syncthreads();
    if (tid < 128) {
        int b = tid & 15, g = (tid >> 4) & 3, dh = tid >> 6;
        int row = (g << 9) + bid * 2 + dh;
        float s = partial[tid] + partial[tid + 128] + partial[tid + 256] + partial[tid + 384]
                + bi[row] + bh[row];
        gate_lds[b * 8 + dh * 4 + g] = s;
    }
    __syncthreads();
    if (tid < 32) {
        int b = tid & 15, dh = tid >> 4;
        int d = bid * 2 + dh;
        float gi = gate_lds[b * 8 + dh * 4 + 0];
        float gf = gate_lds[b * 8 + dh * 4 + 1];
        float gg = gate_lds[b * 8 + dh * 4 + 2];
        float go = gate_lds[b * 8 + dh * 4 + 3];
        float cn = sigf(gf) * c_reg + sigf(gi) * tanhf(gg);
        float hn = sigf(go) * tanhf(cn);
        c_reg = cn;
        st_dev(hout + b * H + d, hn);     // sc1: visible to all blocks after barrier
    }
}

// Persistent fused kernel: all T=300 steps, 3 grid barriers per step, zero fences.
__global__ __launch_bounds__(512) void fused_kernel(
    const float* __restrict__ x,  const float* __restrict__ Wt,
    const float* __restrict__ bpred,
    const float* __restrict__ Wih, const float* __restrict__ Whh,
    const float* __restrict__ bih, const float* __restrict__ bhh,
    float* __restrict__ ws, float* __restrict__ out)
{
    __shared__ __align__(16) float e_lds[B * LSTR];
    __shared__ __align__(16) float h_lds[B * LSTR];
    __shared__ float partial[512];
    __shared__ float gate_lds[B * 8];
    __shared__ float rv[256];
    __shared__ int   ri[256];
    __shared__ int   idx_lds[B];
    __shared__ float red_v[512];
    __shared__ int   red_i[512];

    const int tid = threadIdx.x, bid = blockIdx.x;
    unsigned* flags = (unsigned*)ws + WS_BAR;
    float* pval = ws + WS_PVAL;
    int*   pidx = (int*)(ws + WS_PIDX);
    unsigned ep = 0;
    float c_l0 = 0.0f, c_l1 = 0.0f;       // block-private LSTM cell state (tid<32)

    for (int t = 0; t < T; ++t) {
        const int rb = t & 1, wb = rb ^ 1;

        // ================= phase A: layer 0 =================
        if (t > 0) {
            // redundant per-block argmax reduce over 256 partials (sc1 reads)
            if (tid < 256) {
                int b = tid & 15, ch = tid >> 4;
                float bv = -1e30f; int bx = 0x7fffffff;
                for (int j = 0; j < 16; ++j) {
                    int blk = ch * 16 + j;
                    float v = ld_dev(&pval[blk * 16 + b]);
                    int   i = ld_devi(&pidx[blk * 16 + b]);
                    if (v > bv || (v == bv && i < bx)) { bv = v; bx = i; }
                }
                rv[tid] = bv; ri[tid] = bx;
            }
            __syncthreads();
            if (tid < 16) {
                float bv = -1e30f; int bx = 0x7fffffff;
                for (int ch = 0; ch < 16; ++ch) {
                    float v = rv[ch * 16 + tid]; int i = ri[ch * 16 + tid];
                    if (v > bv || (v == bv && i < bx)) { bv = v; bx = i; }
                }
                idx_lds[tid] = bx;
            }
            __syncthreads();
        }
        lstm_layer(tid, bid,
                   Wih, Whh, bih, bhh,
                   ws + WS_H0 + rb * 8192, c_l0, ws + WS_H0 + wb * 8192,
                   x, Wt, idx_lds, (t > 0) ? 1 : 0,
                   e_lds, h_lds, partial, gate_lds);
        gridbar(flags, ++ep);

        // ================= phase B: layer 1 =================
        lstm_layer(tid, bid,
                   Wih + (long)G4 * H, Whh + (long)G4 * H, bih + G4, bhh + G4,
                   ws + WS_H1 + rb * 8192, c_l1, ws + WS_H1 + wb * 8192,
                   ws + WS_H0 + wb * 8192, Wt, idx_lds, 0,
                   e_lds, h_lds, partial, gate_lds);
        gridbar(flags, ++ep);

        // ================= phase C: logits + partial argmax =================
        {
            const float* h1 = ws + WS_H1 + wb * 8192;
            for (int i = 0; i < 4; ++i) {
                int j = tid + 512 * i;                // 2048 float4-slots
                int b = j >> 7, k4 = (j & 127) << 2;
                const float* s = h1 + b * H + k4;
                float4 hv;
                hv.x = ld_dev(s + 0); hv.y = ld_dev(s + 1);
                hv.z = ld_dev(s + 2); hv.w = ld_dev(s + 3);
                *(float4*)&h_lds[b * LSTR + k4] = hv;
            }
        }
        __syncthreads();
        {
            const int tb = tid & 15, tv = tid >> 4;
            const int vbase = bid * VPB;
            const int v0 = vbase + tv;
            const bool val3 = (tv + 96) < VPB;        // tv < 29
            const float* w0 = Wt + (long)v0 * H;
            const long off3 = val3 ? (long)96 * H : 0;
            const float* hp = &h_lds[tb * LSTR];

            float acc0 = 0.f, acc1 = 0.f, acc2 = 0.f, acc3 = 0.f;
            #pragma unroll 4
            for (int k = 0; k < H; k += 4) {
                float4 hv = *(const float4*)(hp + k);
                float4 a = *(const float4*)(w0 + k);
                acc0 += a.x * hv.x + a.y * hv.y + a.z * hv.z + a.w * hv.w;
                float4 b2 = *(const float4*)(w0 + 32 * H + k);
                acc1 += b2.x * hv.x + b2.y * hv.y + b2.z * hv.z + b2.w * hv.w;
                float4 c2 = *(const float4*)(w0 + 64 * H + k);
                acc2 += c2.x * hv.x + c2.y * hv.y + c2.z * hv.z + c2.w * hv.w;
                float4 d2 = *(const float4*)(w0 + off3 + k);
                acc3 += d2.x * hv.x + d2.y * hv.y + d2.z * hv.z + d2.w * hv.w;
            }

            const long obase = ((long)tb * T + t) * (long)V;
            float l0 = acc0 + bpred[v0];
            float l1 = acc1 + bpred[v0 + 32];
            float l2 = acc2 + bpred[v0 + 64];
            out[obase + v0]      = l0;    // normal stores: host reads after kernel end
            out[obase + v0 + 32] = l1;
            out[obase + v0 + 64] = l2;
            float bv = l0; int bx = v0;
            if (l1 > bv) { bv = l1; bx = v0 + 32; }
            if (l2 > bv) { bv = l2; bx = v0 + 64; }
            if (val3) {
                float l3 = acc3 + bpred[v0 + 96];
                out[obase + v0 + 96] = l3;
                if (l3 > bv) { bv = l3; bx = v0 + 96; }
            }
            red_v[tid] = bv; red_i[tid] = bx;
        }
        __syncthreads();
        if (tid < 16) {
            int b = tid; float bbv = -1e30f; int bbi = 0x7fffffff;
            for (int q = 0; q < 32; ++q) {
                float v = red_v[q * 16 + b]; int i = red_i[q * 16 + b];
                if (v > bbv || (v == bbv && i < bbi)) { bbv = v; bbi = i; }
            }
            st_dev (&pval[bid * 16 + b], bbv);
            st_devi(&pidx[bid * 16 + b], bbi);
        }
        gridbar(flags, ++ep);
    }
}

extern "C" void kernel_launch(void* const* d_in, const int* in_sizes, int n_in,
                              void* d_out, int out_size, void* d_ws, size_t ws_size,
                              hipStream_t stream) {
    const float* x   = (const float*)d_in[0];
    const float* Wt  = (const float*)d_in[1];
    const float* bp  = (const float*)d_in[2];
    const float* Wih = (const float*)d_in[3];
    const float* Whh = (const float*)d_in[4];
    const float* bih = (const float*)d_in[5];
    const float* bhh = (const float*)d_in[6];
    float* out = (float*)d_out;
    float* ws  = (float*)d_ws;
    (void)in_sizes; (void)n_in; (void)out_size; (void)ws_size;

    // Zero LSTM state (h), argmax partials, and barrier flags every call.
    hipMemsetAsync(d_ws, 0, (size_t)WS_FLOATS * sizeof(float), stream);

    void* args[] = { (void*)&x, (void*)&Wt, (void*)&bp, (void*)&Wih, (void*)&Whh,
                     (void*)&bih, (void*)&bhh, (void*)&ws, (void*)&out };
    hipLaunchCooperativeKernel((void*)fused_kernel, dim3(NBLK), dim3(512),
                               args, 0, stream);
}